// Round 4
// baseline (224.112 us; speedup 1.0000x reference)
//
#include <hip/hip_runtime.h>
#include <hip/hip_bf16.h>

#define EMB 768
#define NH 8
#define DH 96
#define BATCH 8
#define SEQ 1024
#define M_TOT (BATCH * SEQ)   // 8192 rows of x
#define NCOLS (3 * EMB)       // q(768) | k(768) | v(768) output channels

typedef float f32x4 __attribute__((ext_vector_type(4)));
typedef __bf16 bf16x8 __attribute__((ext_vector_type(8)));

__device__ __forceinline__ unsigned short f2bf_bits(float f) {
  __hip_bfloat16 b = __float2bfloat16(f);
  return *reinterpret_cast<unsigned short*>(&b);
}

__device__ __forceinline__ void gload_lds16(const void* g, void* l) {
  // async global->LDS, 16B per lane; LDS dest must be wave-uniform base (+lane*16 by HW)
  __builtin_amdgcn_global_load_lds(
      (__attribute__((address_space(1))) void*)(g),
      (__attribute__((address_space(3))) void*)(l), 16, 0, 0);
}

// ---------------- prep: x fp32 -> bf16 ----------------
__global__ void prep_x_kernel(const float* __restrict__ x, __hip_bfloat16* __restrict__ xb) {
  const int n4 = M_TOT * EMB / 4;
  int i = blockIdx.x * blockDim.x + threadIdx.x;
  if (i < n4) {
    f32x4 v = reinterpret_cast<const f32x4*>(x)[i];
    ushort4 o;
    o.x = f2bf_bits(v[0]);
    o.y = f2bf_bits(v[1]);
    o.z = f2bf_bits(v[2]);
    o.w = f2bf_bits(v[3]);
    reinterpret_cast<ushort4*>(xb)[i] = o;
  }
}

// ---------------- prep: permuted weights -> bf16, bias fp32 ----------------
__global__ void prep_w_kernel(const float* __restrict__ qkv_w, const float* __restrict__ qkv_b,
                              const float* __restrict__ val_w, const float* __restrict__ val_b,
                              __hip_bfloat16* __restrict__ Wall, float* __restrict__ bias) {
  const float inv_s = 0.03608439182435161f;  // 1/sqrt(768)
  int idx = blockIdx.x * 256 + threadIdx.x;
  if (idx >= NCOLS * EMB) return;
  int r = idx / EMB;
  int c = idx - r * EMB;
  float v;
  if (r < EMB) {
    int h = r / DH, d = r - h * DH;
    int src = h * 192 + 2 * d;
    v = qkv_w[(size_t)src * EMB + c] * inv_s;
    if (c == 0) bias[r] = qkv_b[src] * inv_s;
  } else if (r < 2 * EMB) {
    int r2 = r - EMB;
    int h = r2 / DH, d = r2 - h * DH;
    int src = h * 192 + 2 * d + 1;
    v = qkv_w[(size_t)src * EMB + c];
    if (c == 0) bias[r] = qkv_b[src];
  } else {
    int r3 = r - 2 * EMB;
    v = val_w[(size_t)r3 * EMB + c];
    if (c == 0) bias[r] = val_b[r3];
  }
  Wall[idx] = __float2bfloat16(v);
}

// ---------------- fused projection GEMM (m97-structure, 128x128, BK=32) ----------------
__global__ __launch_bounds__(256) void gemm_kernel(
    const __hip_bfloat16* __restrict__ xb, const __hip_bfloat16* __restrict__ Wall,
    const float* __restrict__ bias, __hip_bfloat16* __restrict__ q_ws,
    __hip_bfloat16* __restrict__ k_ws, float* __restrict__ vout) {
  __shared__ __hip_bfloat16 As[128 * 32];
  __shared__ __hip_bfloat16 Bs[128 * 32];
  const int tid = threadIdx.x;
  const int w = tid >> 6, l = tid & 63;
  const int m0 = blockIdx.x * 128;
  const int n0 = blockIdx.y * 128;
  const int wr = w >> 1, wc = w & 1;

  f32x4 acc[4][4] = {};

  const int sr0 = (w * 2 + 0) * 16 + (l >> 2);
  const int sr1 = (w * 2 + 1) * 16 + (l >> 2);
  const int sc = (l & 3) * 8;

  for (int kt = 0; kt < EMB / 32; ++kt) {
    const int k0 = kt * 32;
    gload_lds16(xb + (size_t)(m0 + sr0) * EMB + k0 + sc, (void*)(As + (w * 2 + 0) * 512));
    gload_lds16(xb + (size_t)(m0 + sr1) * EMB + k0 + sc, (void*)(As + (w * 2 + 1) * 512));
    gload_lds16(Wall + (size_t)(n0 + sr0) * EMB + k0 + sc, (void*)(Bs + (w * 2 + 0) * 512));
    gload_lds16(Wall + (size_t)(n0 + sr1) * EMB + k0 + sc, (void*)(Bs + (w * 2 + 1) * 512));
    __syncthreads();

    bf16x8 af[4], bfr[4];
#pragma unroll
    for (int t = 0; t < 4; ++t) {
      af[t] = *reinterpret_cast<const bf16x8*>(As + (wr * 64 + t * 16 + (l & 15)) * 32 + (l >> 4) * 8);
      bfr[t] = *reinterpret_cast<const bf16x8*>(Bs + (wc * 64 + t * 16 + (l & 15)) * 32 + (l >> 4) * 8);
    }
#pragma unroll
    for (int i = 0; i < 4; ++i)
#pragma unroll
      for (int j = 0; j < 4; ++j)
        acc[i][j] = __builtin_amdgcn_mfma_f32_16x16x32_bf16(af[i], bfr[j], acc[i][j], 0, 0, 0);
    __syncthreads();
  }

  const int rowbase = m0 + wr * 64;
  const int colbase = n0 + wc * 64;
#pragma unroll
  for (int j = 0; j < 4; ++j) {
    const int n = colbase + j * 16 + (l & 15);
    const float bb = bias[n];
#pragma unroll
    for (int i = 0; i < 4; ++i) {
#pragma unroll
      for (int q = 0; q < 4; ++q) {
        const int m = rowbase + i * 16 + (l >> 4) * 4 + q;
        const float v = acc[i][j][q] + bb;
        if (n0 >= 2 * EMB) {
          vout[(size_t)m * EMB + (n - 2 * EMB)] = v;
        } else if (n0 >= EMB) {
          k_ws[(size_t)m * EMB + (n - EMB)] = __float2bfloat16(v);
        } else {
          q_ws[(size_t)m * EMB + n] = __float2bfloat16(v);
        }
      }
    }
  }
}

// ---------------- fused QK^T + softmax, swapped-operand MFMA, 8 waves ----------------
// grid (SEQ/16, NH*BATCH) with h = bh>>3, b = bh&7 (b fast -> rel[h] rows L2-resident
// and the 8 blocks sharing identical rel rows are 64 apart -> same XCD).
// Block: 16 q-rows x 1024 k-cols; wave w owns cols [w*128, w*128+128).
// mfma(K_frag, Q_frag): lane (lr=l>>4, lc=l&15) holds acc[ct][j] =
// score(q = row0+lc, k = w*128 + ct*16 + lr*4 + j) -> f32x4 rel reads + energy writes.
// Single-barrier softmax: per-wave (m_w, s_w) -> LDS -> M, S = sum s_w*exp(m_w-M).
__global__ __launch_bounds__(512) void attn_kernel(
    const __hip_bfloat16* __restrict__ q_ws, const __hip_bfloat16* __restrict__ k_ws,
    const float* __restrict__ rel, float* __restrict__ eout) {
  __shared__ float redm[16][8];
  __shared__ float reds[16][8];
  const int tid = threadIdx.x;
  const int w = tid >> 6, l = tid & 63;
  const int rb = blockIdx.x;
  const int bh = blockIdx.y;
  const int h = bh >> 3, b = bh & 7;
  const int row0 = rb * 16;
  const int lr = l >> 4;   // k sub-group 0..3
  const int lc = l & 15;   // q-row within tile

  // ---- Q fragments (B-operand): q-row = row0+lc, pre-scaled by 1/sqrt(768) ----
  const __hip_bfloat16* qbase = q_ws + ((size_t)(b * SEQ + row0 + lc)) * EMB + h * DH;
  bf16x8 qf[3];
#pragma unroll
  for (int kc = 0; kc < 3; ++kc)
    qf[kc] = *reinterpret_cast<const bf16x8*>(qbase + kc * 32 + lr * 8);

  // ---- QK^T into registers (A-operand = K rows) ----
  const __hip_bfloat16* kbase = k_ws + ((size_t)(b * SEQ + w * 128 + lc)) * EMB + h * DH;
  f32x4 acc[8];
  __builtin_amdgcn_s_setprio(1);
#pragma unroll
  for (int ct = 0; ct < 8; ++ct) {
    const __hip_bfloat16* kb = kbase + (size_t)(ct * 16) * EMB;
    f32x4 a = {0.f, 0.f, 0.f, 0.f};
#pragma unroll
    for (int kc = 0; kc < 3; ++kc) {
      bf16x8 kf = *reinterpret_cast<const bf16x8*>(kb + kc * 32 + lr * 8);
      a = __builtin_amdgcn_mfma_f32_16x16x32_bf16(kf, qf[kc], a, 0, 0, 0);
    }
    acc[ct] = a;
  }
  __builtin_amdgcn_s_setprio(0);

  // ---- add rel_pos (f32x4, issue all loads first), wave-local max ----
  const float* relp = rel + ((size_t)h * SEQ + row0 + lc) * SEQ + w * 128 + lr * 4;
  f32x4 r[8];
#pragma unroll
  for (int ct = 0; ct < 8; ++ct) r[ct] = *reinterpret_cast<const f32x4*>(relp + ct * 16);
  float mx = -3.4e38f;
#pragma unroll
  for (int ct = 0; ct < 8; ++ct) {
    acc[ct] = acc[ct] + r[ct];
    mx = fmaxf(mx, fmaxf(fmaxf(acc[ct][0], acc[ct][1]), fmaxf(acc[ct][2], acc[ct][3])));
  }
  // combine the 4 lr-groups (same q-row lc) within the wave
  mx = fmaxf(mx, __shfl_xor(mx, 16));
  mx = fmaxf(mx, __shfl_xor(mx, 32));

  // ---- exp with wave-local max, wave-local sum ----
  float sm = 0.f;
#pragma unroll
  for (int ct = 0; ct < 8; ++ct) {
#pragma unroll
    for (int j = 0; j < 4; ++j) {
      float e = __expf(acc[ct][j] - mx);
      acc[ct][j] = e;
      sm += e;
    }
  }
  sm += __shfl_xor(sm, 16);
  sm += __shfl_xor(sm, 32);
  if (l < 16) {
    redm[lc][w] = mx;
    reds[lc][w] = sm;
  }
  __syncthreads();

  // ---- global max + corrected sum, per-wave rescale factor ----
  float M = -3.4e38f;
#pragma unroll
  for (int i = 0; i < 8; ++i) M = fmaxf(M, redm[lc][i]);
  float S = 0.f;
#pragma unroll
  for (int i = 0; i < 8; ++i) S += reds[lc][i] * __expf(redm[lc][i] - M);
  const float rinv = __expf(mx - M) / S;

  // ---- normalized f32x4 write ----
  float* op = eout + ((size_t)(b * NH + h) * SEQ + row0 + lc) * SEQ + w * 128 + lr * 4;
#pragma unroll
  for (int ct = 0; ct < 8; ++ct) {
    f32x4 v = acc[ct] * rinv;
    *reinterpret_cast<f32x4*>(op + ct * 16) = v;
  }
}

extern "C" void kernel_launch(void* const* d_in, const int* in_sizes, int n_in,
                              void* d_out, int out_size, void* d_ws, size_t ws_size,
                              hipStream_t stream) {
  const float* x = (const float*)d_in[0];
  const float* rel = (const float*)d_in[1];
  const float* qkv_w = (const float*)d_in[2];
  const float* qkv_b = (const float*)d_in[3];
  const float* val_w = (const float*)d_in[4];
  const float* val_b = (const float*)d_in[5];
  float* out = (float*)d_out;

  char* ws = (char*)d_ws;
  __hip_bfloat16* xb = (__hip_bfloat16*)(ws);                  // 12,582,912
  __hip_bfloat16* Wall = (__hip_bfloat16*)(ws + 12582912);     //  3,538,944
  float* bias = (float*)(ws + 16121856);                       //      9,216
  __hip_bfloat16* q_ws = (__hip_bfloat16*)(ws + 16131072);     // 12,582,912
  __hip_bfloat16* k_ws = (__hip_bfloat16*)(ws + 28713984);     // 12,582,912

  float* vout = out;                       // [8192][768] values
  float* eout = out + (size_t)M_TOT * EMB; // [64][1024][1024] energy

  prep_x_kernel<<<dim3(M_TOT * EMB / 4 / 256), dim3(256), 0, stream>>>(x, xb);
  prep_w_kernel<<<dim3(NCOLS * EMB / 256), dim3(256), 0, stream>>>(qkv_w, qkv_b, val_w, val_b,
                                                                   Wall, bias);
  gemm_kernel<<<dim3(M_TOT / 128, NCOLS / 128), dim3(256), 0, stream>>>(xb, Wall, bias, q_ws,
                                                                        k_ws, vout);
  attn_kernel<<<dim3(SEQ / 16, NH * BATCH), dim3(512), 0, stream>>>(q_ws, k_ws, rel, eout);
}

// Round 5
// 190.086 us; speedup vs baseline: 1.1790x; 1.1790x over previous
//
#include <hip/hip_runtime.h>
#include <hip/hip_bf16.h>

#define EMB 768
#define NH 8
#define DH 96
#define BATCH 8
#define SEQ 1024
#define M_TOT (BATCH * SEQ)   // 8192 rows of x
#define NCOLS (3 * EMB)       // q(768) | k(768) | v(768) output channels

typedef float f32x4 __attribute__((ext_vector_type(4)));
typedef __bf16 bf16x8 __attribute__((ext_vector_type(8)));

__device__ __forceinline__ unsigned short f2bf_bits(float f) {
  __hip_bfloat16 b = __float2bfloat16(f);
  return *reinterpret_cast<unsigned short*>(&b);
}

__device__ __forceinline__ void gload_lds16(const void* g, void* l) {
  // async global->LDS, 16B per lane; LDS dest must be wave-uniform base (+lane*16 by HW)
  __builtin_amdgcn_global_load_lds(
      (__attribute__((address_space(1))) void*)(g),
      (__attribute__((address_space(3))) void*)(l), 16, 0, 0);
}

// ---------------- prep: x fp32 -> bf16 ----------------
__global__ void prep_x_kernel(const float* __restrict__ x, __hip_bfloat16* __restrict__ xb) {
  const int n4 = M_TOT * EMB / 4;
  int i = blockIdx.x * blockDim.x + threadIdx.x;
  if (i < n4) {
    f32x4 v = reinterpret_cast<const f32x4*>(x)[i];
    ushort4 o;
    o.x = f2bf_bits(v[0]);
    o.y = f2bf_bits(v[1]);
    o.z = f2bf_bits(v[2]);
    o.w = f2bf_bits(v[3]);
    reinterpret_cast<ushort4*>(xb)[i] = o;
  }
}

// ---------------- prep: permuted weights -> bf16, bias fp32 ----------------
__global__ void prep_w_kernel(const float* __restrict__ qkv_w, const float* __restrict__ qkv_b,
                              const float* __restrict__ val_w, const float* __restrict__ val_b,
                              __hip_bfloat16* __restrict__ Wall, float* __restrict__ bias) {
  const float inv_s = 0.03608439182435161f;  // 1/sqrt(768)
  int idx = blockIdx.x * 256 + threadIdx.x;
  if (idx >= NCOLS * EMB) return;
  int r = idx / EMB;
  int c = idx - r * EMB;
  float v;
  if (r < EMB) {
    int h = r / DH, d = r - h * DH;
    int src = h * 192 + 2 * d;
    v = qkv_w[(size_t)src * EMB + c] * inv_s;
    if (c == 0) bias[r] = qkv_b[src] * inv_s;
  } else if (r < 2 * EMB) {
    int r2 = r - EMB;
    int h = r2 / DH, d = r2 - h * DH;
    int src = h * 192 + 2 * d + 1;
    v = qkv_w[(size_t)src * EMB + c];
    if (c == 0) bias[r] = qkv_b[src];
  } else {
    int r3 = r - 2 * EMB;
    v = val_w[(size_t)r3 * EMB + c];
    if (c == 0) bias[r] = val_b[r3];
  }
  Wall[idx] = __float2bfloat16(v);
}

// ---------------- fused projection GEMM (m97-structure, 128x128, BK=32) ----------------
// q/k epilogue now writes head-packed layout: [b][h][n][96] bf16.
__global__ __launch_bounds__(256) void gemm_kernel(
    const __hip_bfloat16* __restrict__ xb, const __hip_bfloat16* __restrict__ Wall,
    const float* __restrict__ bias, __hip_bfloat16* __restrict__ qhead,
    __hip_bfloat16* __restrict__ khead, float* __restrict__ vout) {
  __shared__ __hip_bfloat16 As[128 * 32];
  __shared__ __hip_bfloat16 Bs[128 * 32];
  const int tid = threadIdx.x;
  const int w = tid >> 6, l = tid & 63;
  const int m0 = blockIdx.x * 128;
  const int n0 = blockIdx.y * 128;
  const int wr = w >> 1, wc = w & 1;

  f32x4 acc[4][4] = {};

  const int sr0 = (w * 2 + 0) * 16 + (l >> 2);
  const int sr1 = (w * 2 + 1) * 16 + (l >> 2);
  const int sc = (l & 3) * 8;

  for (int kt = 0; kt < EMB / 32; ++kt) {
    const int k0 = kt * 32;
    gload_lds16(xb + (size_t)(m0 + sr0) * EMB + k0 + sc, (void*)(As + (w * 2 + 0) * 512));
    gload_lds16(xb + (size_t)(m0 + sr1) * EMB + k0 + sc, (void*)(As + (w * 2 + 1) * 512));
    gload_lds16(Wall + (size_t)(n0 + sr0) * EMB + k0 + sc, (void*)(Bs + (w * 2 + 0) * 512));
    gload_lds16(Wall + (size_t)(n0 + sr1) * EMB + k0 + sc, (void*)(Bs + (w * 2 + 1) * 512));
    __syncthreads();

    bf16x8 af[4], bfr[4];
#pragma unroll
    for (int t = 0; t < 4; ++t) {
      af[t] = *reinterpret_cast<const bf16x8*>(As + (wr * 64 + t * 16 + (l & 15)) * 32 + (l >> 4) * 8);
      bfr[t] = *reinterpret_cast<const bf16x8*>(Bs + (wc * 64 + t * 16 + (l & 15)) * 32 + (l >> 4) * 8);
    }
#pragma unroll
    for (int i = 0; i < 4; ++i)
#pragma unroll
      for (int j = 0; j < 4; ++j)
        acc[i][j] = __builtin_amdgcn_mfma_f32_16x16x32_bf16(af[i], bfr[j], acc[i][j], 0, 0, 0);
    __syncthreads();
  }

  const int rowbase = m0 + wr * 64;
  const int colbase = n0 + wc * 64;
#pragma unroll
  for (int j = 0; j < 4; ++j) {
    const int n = colbase + j * 16 + (l & 15);
    const float bb = bias[n];
#pragma unroll
    for (int i = 0; i < 4; ++i) {
#pragma unroll
      for (int q = 0; q < 4; ++q) {
        const int m = rowbase + i * 16 + (l >> 4) * 4 + q;
        const float v = acc[i][j][q] + bb;
        if (n0 >= 2 * EMB) {
          vout[(size_t)m * EMB + (n - 2 * EMB)] = v;
        } else {
          const int nn = (n0 >= EMB) ? (n - EMB) : n;
          const int hh = nn / DH, dd = nn - hh * DH;
          const size_t off = ((size_t)((m >> 10) * NH + hh) * SEQ + (m & 1023)) * DH + dd;
          if (n0 >= EMB) khead[off] = __float2bfloat16(v);
          else qhead[off] = __float2bfloat16(v);
        }
      }
    }
  }
}

// ---------------- fused QK^T + softmax: all global traffic coalesced ----------------
// 1-D grid 4096 blocks (decoded so the 8 b-blocks sharing rel rows land on one XCD),
// 512 threads = 8 waves. Block: 16 q-rows x 1024 k-cols.
// K chunk loop (8 x 128 rows): cooperative linear global_load_lds (24.5KB/chunk);
// wave w computes col-tile c*128 + w*16 via mfma(K,Q) (lane: q-row=lc, k=w*16+lr*4+j).
// rel staged per chunk via coalesced f32x4 -> padded LDS. Energy stored via a
// block-wide XOR-swizzled 64KB LDS transpose -> 512B-contiguous f32x4 stores.
__global__ __launch_bounds__(512, 4) void attn_kernel(
    const __hip_bfloat16* __restrict__ qhead, const __hip_bfloat16* __restrict__ khead,
    const float* __restrict__ rel, float* __restrict__ eout) {
  __shared__ alignas(16) char smem[65536];
  __shared__ float redm[16][8];
  __shared__ float reds[16][8];
  __hip_bfloat16* Kb = (__hip_bfloat16*)smem;               // phase A: [128][96] bf16 chunk
  float* rel_lds = (float*)(smem + 24576);                  // phase A: [16][132] f32
  __hip_bfloat16* qlds = (__hip_bfloat16*)(smem + 33024);   // phase A: [16][96] bf16
  float* Sb = (float*)smem;                                 // phase B: [16][1024] f32

  const int t = threadIdx.x;
  const int w = t >> 6, l = t & 63;
  const int lr = l >> 4, lc = l & 15;
  // grid decode: flat = u*64 + b*8 + r8 ; (h,rb) = g = u*8+r8 -> b-variants share XCD
  const int flat = blockIdx.x;
  const int u = flat >> 6;
  const int b = (flat >> 3) & 7;
  const int g = u * 8 + (flat & 7);
  const int h = g >> 6;
  const int rb = g & 63;
  const int row0 = rb * 16;
  const int rowt = t >> 5, st = t & 31;  // staging/store mapping: 32 lanes per row

  // ---- stage Q (16 rows x 192B = 3KB, linear both sides) ----
  const __hip_bfloat16* qsrc = qhead + ((size_t)(b * NH + h) * SEQ + row0) * DH;
  if (t < 192) gload_lds16(qsrc + t * 8, smem + 33024 + w * 1024);
  __syncthreads();

  bf16x8 qf[3];
#pragma unroll
  for (int kc = 0; kc < 3; ++kc)
    qf[kc] = *reinterpret_cast<const bf16x8*>(qlds + lc * DH + kc * 32 + lr * 8);

  const __hip_bfloat16* ksrc = khead + (size_t)(b * NH + h) * SEQ * DH;
  const float* relsrc = rel + ((size_t)h * SEQ + row0 + rowt) * SEQ + st * 4;

  f32x4 relreg = *reinterpret_cast<const f32x4*>(relsrc);
  f32x4 acc[8];

#pragma unroll
  for (int c = 0; c < 8; ++c) {
    // stage K chunk c: 24576B, linear global & linear LDS
#pragma unroll
    for (int r = 0; r < 3; ++r)
      gload_lds16(ksrc + (size_t)c * 12288 + r * 4096 + t * 8, smem + r * 8192 + w * 1024);
    // rel chunk c -> padded LDS (coalesced load was issued last iteration)
    *reinterpret_cast<f32x4*>(rel_lds + rowt * 132 + st * 4) = relreg;
    __syncthreads();  // K chunk + rel tile ready
    if (c < 7) relreg = *reinterpret_cast<const f32x4*>(relsrc + (size_t)(c + 1) * 128);
    f32x4 a = {0.f, 0.f, 0.f, 0.f};
    __builtin_amdgcn_s_setprio(1);
#pragma unroll
    for (int kc = 0; kc < 3; ++kc) {
      bf16x8 kf = *reinterpret_cast<const bf16x8*>(Kb + (w * 16 + lc) * DH + kc * 32 + lr * 8);
      a = __builtin_amdgcn_mfma_f32_16x16x32_bf16(kf, qf[kc], a, 0, 0, 0);
    }
    __builtin_amdgcn_s_setprio(0);
    a = a + *reinterpret_cast<const f32x4*>(rel_lds + lc * 132 + w * 16 + lr * 4);
    acc[c] = a;
    __syncthreads();  // all reads done before next chunk overwrites
  }

  // ---- softmax reductions (scores: q-row = row0+lc, k-col = c*128+w*16+lr*4+j) ----
  float mx = -3.4e38f;
#pragma unroll
  for (int c = 0; c < 8; ++c)
    mx = fmaxf(mx, fmaxf(fmaxf(acc[c][0], acc[c][1]), fmaxf(acc[c][2], acc[c][3])));
  mx = fmaxf(mx, __shfl_xor(mx, 16));
  mx = fmaxf(mx, __shfl_xor(mx, 32));
  if (l < 16) redm[lc][w] = mx;
  __syncthreads();
  float M = redm[lc][0];
#pragma unroll
  for (int i = 1; i < 8; ++i) M = fmaxf(M, redm[lc][i]);

  float sm = 0.f;
#pragma unroll
  for (int c = 0; c < 8; ++c) {
#pragma unroll
    for (int j = 0; j < 4; ++j) {
      float e = __expf(acc[c][j] - M);
      acc[c][j] = e;
      sm += e;
    }
  }
  sm += __shfl_xor(sm, 16);
  sm += __shfl_xor(sm, 32);
  if (l < 16) reds[lc][w] = sm;
  __syncthreads();
  float S = 0.f;
#pragma unroll
  for (int i = 0; i < 8; ++i) S += reds[lc][i];
  const float rinv = 1.0f / S;

  // ---- phase B: swizzled LDS transpose -> coalesced stores ----
#pragma unroll
  for (int c = 0; c < 8; ++c) {
    f32x4 v = acc[c] * rinv;
    const int col = c * 128 + w * 16 + lr * 4;
    *reinterpret_cast<f32x4*>(Sb + lc * 1024 + (col ^ ((lc & 7) << 2))) = v;
  }
  __syncthreads();
  float* ebase = eout + ((size_t)(b * NH + h) * SEQ + row0 + rowt) * SEQ;
#pragma unroll
  for (int p = 0; p < 8; ++p) {
    const int col = p * 128 + st * 4;
    f32x4 v = *reinterpret_cast<const f32x4*>(Sb + rowt * 1024 + (col ^ ((rowt & 7) << 2)));
    *reinterpret_cast<f32x4*>(ebase + col) = v;
  }
}

extern "C" void kernel_launch(void* const* d_in, const int* in_sizes, int n_in,
                              void* d_out, int out_size, void* d_ws, size_t ws_size,
                              hipStream_t stream) {
  const float* x = (const float*)d_in[0];
  const float* rel = (const float*)d_in[1];
  const float* qkv_w = (const float*)d_in[2];
  const float* qkv_b = (const float*)d_in[3];
  const float* val_w = (const float*)d_in[4];
  const float* val_b = (const float*)d_in[5];
  float* out = (float*)d_out;

  char* ws = (char*)d_ws;
  __hip_bfloat16* xb = (__hip_bfloat16*)(ws);                  // 12,582,912
  __hip_bfloat16* Wall = (__hip_bfloat16*)(ws + 12582912);     //  3,538,944
  float* bias = (float*)(ws + 16121856);                       //      9,216
  __hip_bfloat16* qhead = (__hip_bfloat16*)(ws + 16131072);    // 12,582,912  [b][h][n][96]
  __hip_bfloat16* khead = (__hip_bfloat16*)(ws + 28713984);    // 12,582,912  [b][h][n][96]

  float* vout = out;                       // [8192][768] values
  float* eout = out + (size_t)M_TOT * EMB; // [64][1024][1024] energy

  prep_x_kernel<<<dim3(M_TOT * EMB / 4 / 256), dim3(256), 0, stream>>>(x, xb);
  prep_w_kernel<<<dim3(NCOLS * EMB / 256), dim3(256), 0, stream>>>(qkv_w, qkv_b, val_w, val_b,
                                                                   Wall, bias);
  gemm_kernel<<<dim3(M_TOT / 128, NCOLS / 128), dim3(256), 0, stream>>>(xb, Wall, bias, qhead,
                                                                        khead, vout);
  attn_kernel<<<dim3(SEQ / 16 * NH * BATCH), dim3(512), 0, stream>>>(qhead, khead, rel, eout);
}